// Round 3
// baseline (1246.269 us; speedup 1.0000x reference)
//
#include <hip/hip_runtime.h>
#include <hip/hip_bf16.h>
#include <stdint.h>

#define NTOK 4096
#define DM   2048
#define DF   4096
#define NEXP 8
#define NPAD 10240   // max padded rows: 8192 + 8*255 rounded up
#define NPTILE 40    // NPAD / 256

typedef __attribute__((ext_vector_type(4))) float f32x4;
typedef __attribute__((ext_vector_type(8))) short s16x8;
typedef __attribute__((ext_vector_type(4))) int   i32x4;
typedef __attribute__((ext_vector_type(2))) int   i32x2;

__device__ __forceinline__ unsigned short f2bf(float f) {
  union { float f; unsigned u; } x; x.f = f;
  unsigned r = x.u + 0x7fffu + ((x.u >> 16) & 1u);   // RNE to bf16
  return (unsigned short)(r >> 16);
}
__device__ __forceinline__ unsigned pack2(float lo, float hi) {
  __hip_bfloat162 h2 = __float22bfloat162_rn(make_float2(lo, hi));
  return *reinterpret_cast<unsigned*>(&h2);
}
// element (short) offset into a [rows][32] bf16 tile image, 16B-chunk XOR swizzle
__device__ __forceinline__ int swz(int row, int ks) {
  return row * 32 + ((ks ^ ((row >> 1) & 3)) << 3);
}
__device__ __forceinline__ void g2l16(const void* g, void* l) {
  __builtin_amdgcn_global_load_lds(
      (const __attribute__((address_space(1))) void*)g,
      (__attribute__((address_space(3))) void*)l, 16, 0, 0);
}

// ---------------- init / routing ----------------
__global__ void k_zero_out(float* out) {
  int gid = blockIdx.x * 256 + threadIdx.x;
  *(f32x4*)(out + (size_t)gid * 4) = f32x4{0.f, 0.f, 0.f, 0.f};
}

__global__ void k_init(int* tokrow, int* counts, int* cursor) {
  int i = blockIdx.x * 256 + threadIdx.x;
  if (i < NPAD) tokrow[i] = 0;
  if (i < NEXP) { counts[i] = 0; cursor[i] = 0; }
}

__global__ void k_count(const int* __restrict__ idx, int* counts) {
  int t = blockIdx.x * 256 + threadIdx.x;
  if (t >= NTOK) return;
  int e0 = idx[2 * t], e1 = idx[2 * t + 1];
  atomicAdd(&counts[e0], 1);
  if (e1 != e0) atomicAdd(&counts[e1], 1);
}

__global__ void k_scan(const int* __restrict__ counts, int* poff) {
  if (threadIdx.x == 0) {
    int s = 0;
    for (int e = 0; e < NEXP; e++) {
      poff[e] = s;
      s += ((counts[e] + 255) & ~255);
    }
  }
}

__global__ void k_fill(const int* __restrict__ idx, const float* __restrict__ wts,
                       const int* __restrict__ poff, int* cursor,
                       int* tokrow, float* wrow) {
  int t = blockIdx.x * 256 + threadIdx.x;
  if (t >= NTOK) return;
  int e0 = idx[2 * t], e1 = idx[2 * t + 1];
  float w0 = wts[2 * t], w1 = wts[2 * t + 1];
  if (e0 == e1) {
    int g = poff[e0] + atomicAdd(&cursor[e0], 1);
    tokrow[g] = t; wrow[g] = w0 + w1;
  } else {
    int g0 = poff[e0] + atomicAdd(&cursor[e0], 1);
    tokrow[g0] = t; wrow[g0] = w0;
    int g1 = poff[e1] + atomicAdd(&cursor[e1], 1);
    tokrow[g1] = t; wrow[g1] = w1;
  }
}

// ---------------- X -> gathered bf16 swizzled tile images ----------------
// Xg layout: [tile (0..39)][kt (0..63)][256x32 image (8192 shorts)]
__global__ void k_convX(const float* __restrict__ X, const int* __restrict__ tokrow,
                        short* __restrict__ Xg) {
  const int kt = blockIdx.x, tile = blockIdx.y, tid = threadIdx.x;
  const int part = tid & 7;
  short* dst = Xg + (size_t)(tile * 64 + kt) * 8192;
  #pragma unroll
  for (int it = 0; it < 8; it++) {
    int row = it * 32 + (tid >> 3);
    int tok = tokrow[tile * 256 + row];
    f32x4 v = *(const f32x4*)(X + (size_t)tok * DM + kt * 32 + part * 4);
    i32x2 p;
    p[0] = (int)pack2(v[0], v[1]);
    p[1] = (int)pack2(v[2], v[3]);
    int idx = row * 32 + (((part >> 1) ^ ((row >> 1) & 3)) << 3) + (part & 1) * 4;
    *(i32x2*)&dst[idx] = p;
  }
}

// ---------------- W (f32 [K][N]) -> bf16 transposed swizzled tile images ----------------
// dst layout per expert-in-buf z: [nt (N/128)][kt (K/32)][128x32 image (4096 shorts)]
__global__ void k_convW(const float* __restrict__ W_all, short* __restrict__ dstbuf,
                        int e0, int N, int K) {
  const int nt = blockIdx.x, kt = blockIdx.y, z = blockIdx.z;
  const int e = e0 + z;
  const int tid = threadIdx.x;
  const int kl = tid >> 3, ng = (tid & 7) * 16;
  const float* src = W_all + (size_t)e * K * N + (size_t)(kt * 32 + kl) * N + nt * 128 + ng;

  __shared__ __attribute__((aligned(16))) short img[4096];

  f32x4 v0 = ((const f32x4*)src)[0];
  f32x4 v1 = ((const f32x4*)src)[1];
  f32x4 v2 = ((const f32x4*)src)[2];
  f32x4 v3 = ((const f32x4*)src)[3];
  float vv[16];
  *(f32x4*)&vv[0] = v0; *(f32x4*)&vv[4] = v1;
  *(f32x4*)&vv[8] = v2; *(f32x4*)&vv[12] = v3;
  const int ks = kl >> 3, kr = kl & 7;
  #pragma unroll
  for (int j = 0; j < 16; j++) {
    int nl = ng + j;
    img[nl * 32 + ((ks ^ ((nl >> 1) & 3)) << 3) + kr] = (short)f2bf(vv[j]);
  }
  __syncthreads();
  short* dst = dstbuf + ((size_t)(z * (N / 128) + nt) * (K / 32) + kt) * 4096;
  *(i32x4*)&dst[tid * 16]     = *(const i32x4*)&img[tid * 16];
  *(i32x4*)&dst[tid * 16 + 8] = *(const i32x4*)&img[tid * 16 + 8];
}

// ---------------- GEMM1: Hs = swiglu(Xg x Wgt, Xg x Wut), per expert-pair ----------------
__global__ __launch_bounds__(512, 2) void gemm1_kernel(
    const short* __restrict__ Xg, const short* __restrict__ Wgt,
    const short* __restrict__ Wut, const int* __restrict__ counts,
    const int* __restrict__ poff, unsigned short* __restrict__ Hs, int e0) {
  const int z = blockIdx.z, e = e0 + z;
  const int cnt = counts[e];
  const int m0 = blockIdx.y * 256;
  if (m0 >= cnt) return;
  const int nt = blockIdx.x, n0 = nt * 128;
  const int tileIdx = (poff[e] >> 8) + blockIdx.y;

  __shared__ __attribute__((aligned(16))) short As[2][8192];
  __shared__ __attribute__((aligned(16))) short Bs[2][2][4096];

  const int tid = threadIdx.x, wave = tid >> 6, lane = tid & 63;
  const int wm = wave >> 1, wn = wave & 1;
  const int lr = lane & 15, ks = lane >> 4;
  const int bmat = wave >> 2, wv = wave & 3;

  const short* aS = Xg + (size_t)tileIdx * 64 * 8192 + wave * 1024 + lane * 8;
  const short* bS = (bmat ? Wut : Wgt) + (size_t)(z * 32 + nt) * 64 * 4096
                    + wv * 1024 + lane * 8;

  f32x4 accg[4][4], accu[4][4];
  #pragma unroll
  for (int i = 0; i < 4; i++)
    #pragma unroll
    for (int j = 0; j < 4; j++) {
      accg[i][j] = f32x4{0.f, 0.f, 0.f, 0.f};
      accu[i][j] = f32x4{0.f, 0.f, 0.f, 0.f};
    }

  auto stage = [&](int b, int kt) {
    g2l16(aS + (size_t)kt * 8192,       &As[b][wave * 1024]);
    g2l16(aS + (size_t)kt * 8192 + 512, &As[b][wave * 1024 + 512]);
    g2l16(bS + (size_t)kt * 4096,       &Bs[b][bmat][wv * 1024]);
    g2l16(bS + (size_t)kt * 4096 + 512, &Bs[b][bmat][wv * 1024 + 512]);
  };

  stage(0, 0);
  __syncthreads();
  int buf = 0;
  const int nK = DM / 32;
  for (int kt = 0; kt < nK; ++kt) {
    if (kt + 1 < nK) stage(buf ^ 1, kt + 1);
    s16x8 af[4], bg[4], bu[4];
    #pragma unroll
    for (int mi = 0; mi < 4; mi++)
      af[mi] = *(const s16x8*)&As[buf][swz(wm * 64 + mi * 16 + lr, ks)];
    #pragma unroll
    for (int ni = 0; ni < 4; ni++) {
      bg[ni] = *(const s16x8*)&Bs[buf][0][swz(wn * 64 + ni * 16 + lr, ks)];
      bu[ni] = *(const s16x8*)&Bs[buf][1][swz(wn * 64 + ni * 16 + lr, ks)];
    }
    #pragma unroll
    for (int mi = 0; mi < 4; mi++)
      #pragma unroll
      for (int ni = 0; ni < 4; ni++) {
        accg[mi][ni] = __builtin_amdgcn_mfma_f32_16x16x32_bf16(af[mi], bg[ni], accg[mi][ni], 0, 0, 0);
        accu[mi][ni] = __builtin_amdgcn_mfma_f32_16x16x32_bf16(af[mi], bu[ni], accu[mi][ni], 0, 0, 0);
      }
    __syncthreads();
    buf ^= 1;
  }

  // epilogue: silu(g)*u -> Hs in gemm2's swizzled tile-image layout
  const size_t tb = (size_t)tileIdx * 128 * 8192;
  #pragma unroll
  for (int mi = 0; mi < 4; mi++) {
    #pragma unroll
    for (int r = 0; r < 4; r++) {
      int row = wm * 64 + mi * 16 + ks * 4 + r;
      if (m0 + row < cnt) {
        #pragma unroll
        for (int ni = 0; ni < 4; ni++) {
          int col = n0 + wn * 64 + ni * 16 + lr;
          float g = accg[mi][ni][r], u = accu[mi][ni][r];
          float sv = g / (1.f + __expf(-g));
          int ktH = col >> 5, kl = col & 31;
          Hs[tb + (size_t)ktH * 8192 + row * 32 +
             (((kl >> 3) ^ ((row >> 1) & 3)) << 3) + (kl & 7)] = f2bf(sv * u);
        }
      }
    }
  }
}

// ---------------- GEMM2: out += (Hs x Wdt) * w_row (atomic, <=2 adds/elem) ----------------
__global__ __launch_bounds__(512, 2) void gemm2_kernel(
    const unsigned short* __restrict__ Hs, const short* __restrict__ Wdt,
    const int* __restrict__ counts, const int* __restrict__ poff,
    const int* __restrict__ tokrow, const float* __restrict__ wrow,
    float* __restrict__ out, int e0) {
  const int z = blockIdx.z, e = e0 + z;
  const int cnt = counts[e];
  const int m0 = blockIdx.y * 256;
  if (m0 >= cnt) return;
  const int nt = blockIdx.x, n0 = nt * 128;
  const int tileIdx = (poff[e] >> 8) + blockIdx.y;

  __shared__ __attribute__((aligned(16))) short As[2][8192];
  __shared__ __attribute__((aligned(16))) short Bs[2][4096];
  __shared__ float wl[256];
  __shared__ int   tl[256];

  const int tid = threadIdx.x, wave = tid >> 6, lane = tid & 63;
  const int wm = wave >> 1, wn = wave & 1;
  const int lr = lane & 15, ks = lane >> 4;

  if (tid < 256) {
    int rp = poff[e] + m0 + tid;
    wl[tid] = wrow[rp];
    tl[tid] = tokrow[rp];
  }

  const unsigned short* aS = Hs + (size_t)tileIdx * 128 * 8192 + wave * 1024 + lane * 8;
  const short* bS = Wdt + (size_t)(z * 16 + nt) * 128 * 4096 + wave * 512 + lane * 8;

  f32x4 acc[4][4];
  #pragma unroll
  for (int i = 0; i < 4; i++)
    #pragma unroll
    for (int j = 0; j < 4; j++) acc[i][j] = f32x4{0.f, 0.f, 0.f, 0.f};

  auto stage = [&](int b, int kt) {
    g2l16(aS + (size_t)kt * 8192,       &As[b][wave * 1024]);
    g2l16(aS + (size_t)kt * 8192 + 512, &As[b][wave * 1024 + 512]);
    g2l16(bS + (size_t)kt * 4096,       &Bs[b][wave * 512]);
  };

  stage(0, 0);
  __syncthreads();
  int buf = 0;
  const int nK = DF / 32;
  for (int kt = 0; kt < nK; ++kt) {
    if (kt + 1 < nK) stage(buf ^ 1, kt + 1);
    s16x8 af[4], bf_[4];
    #pragma unroll
    for (int mi = 0; mi < 4; mi++)
      af[mi] = *(const s16x8*)&As[buf][swz(wm * 64 + mi * 16 + lr, ks)];
    #pragma unroll
    for (int ni = 0; ni < 4; ni++)
      bf_[ni] = *(const s16x8*)&Bs[buf][swz(wn * 64 + ni * 16 + lr, ks)];
    #pragma unroll
    for (int mi = 0; mi < 4; mi++)
      #pragma unroll
      for (int ni = 0; ni < 4; ni++)
        acc[mi][ni] = __builtin_amdgcn_mfma_f32_16x16x32_bf16(af[mi], bf_[ni], acc[mi][ni], 0, 0, 0);
    __syncthreads();
    buf ^= 1;
  }

  #pragma unroll
  for (int mi = 0; mi < 4; mi++) {
    #pragma unroll
    for (int r = 0; r < 4; r++) {
      int row = wm * 64 + mi * 16 + ks * 4 + r;
      if (m0 + row < cnt) {
        float wgt = wl[row];
        float* obase = out + (size_t)tl[row] * DM + n0 + wn * 64 + lr;
        #pragma unroll
        for (int ni = 0; ni < 4; ni++)
          atomicAdd(obase + ni * 16, acc[mi][ni][r] * wgt);
      }
    }
  }
}

extern "C" void kernel_launch(void* const* d_in, const int* in_sizes, int n_in,
                              void* d_out, int out_size, void* d_ws, size_t ws_size,
                              hipStream_t stream) {
  (void)in_sizes; (void)n_in; (void)out_size; (void)ws_size;
  const float* X   = (const float*)d_in[0];
  const int*   idx = (const int*)d_in[1];
  const float* wts = (const float*)d_in[2];
  const float* Wg  = (const float*)d_in[3];
  const float* Wu  = (const float*)d_in[4];
  const float* Wd  = (const float*)d_in[5];
  float* out = (float*)d_out;

  uint8_t* w = (uint8_t*)d_ws;
  int*   counts = (int*)(w + 0);
  int*   cursor = (int*)(w + 64);
  int*   poff   = (int*)(w + 128);
  int*   tokrow = (int*)(w + 4096);
  float* wrow   = (float*)(w + 45056);
  short* Xg     = (short*)(w + (1ull << 20));                 // 40 MB
  unsigned short* Hs = (unsigned short*)(w + (48ull << 20));  // 80 MB
  short* Wgt    = (short*)(w + (132ull << 20));               // 33.6 MB (2 experts)
  short* Wut    = (short*)(w + (166ull << 20));               // 33.6 MB
  short* Wdt    = (short*)(w + (132ull << 20));               // aliases Wgt (used after all gemm1)

  k_zero_out<<<NTOK * DM / 1024, 256, 0, stream>>>(out);
  k_init<<<NPTILE, 256, 0, stream>>>(tokrow, counts, cursor);
  k_count<<<16, 256, 0, stream>>>(idx, counts);
  k_scan<<<1, 64, 0, stream>>>(counts, poff);
  k_fill<<<16, 256, 0, stream>>>(idx, wts, poff, cursor, tokrow, wrow);
  k_convX<<<dim3(DM / 32, NPTILE), 256, 0, stream>>>(X, tokrow, Xg);

  for (int p = 0; p < 4; p++) {
    int e0 = 2 * p;
    k_convW<<<dim3(DF / 128, DM / 32, 2), 256, 0, stream>>>(Wg, Wgt, e0, DF, DM);
    k_convW<<<dim3(DF / 128, DM / 32, 2), 256, 0, stream>>>(Wu, Wut, e0, DF, DM);
    gemm1_kernel<<<dim3(DF / 128, 16, 2), 512, 0, stream>>>(Xg, Wgt, Wut, counts, poff, Hs, e0);
  }
  for (int p = 0; p < 4; p++) {
    int e0 = 2 * p;
    k_convW<<<dim3(DM / 128, DF / 32, 2), 256, 0, stream>>>(Wd, Wdt, e0, DM, DF);
    gemm2_kernel<<<dim3(DM / 128, 16, 2), 512, 0, stream>>>(Hs, Wdt, counts, poff, tokrow, wrow, out, e0);
  }
}

// Round 4
// 1113.463 us; speedup vs baseline: 1.1193x; 1.1193x over previous
//
#include <hip/hip_runtime.h>
#include <hip/hip_bf16.h>

#define NTOK 4096
#define DM   2048
#define DF   4096
#define NEXP 8

typedef __attribute__((ext_vector_type(4))) float f32x4;
typedef __attribute__((ext_vector_type(8))) short s16x8;
typedef __attribute__((ext_vector_type(4))) int   i32x4;
typedef __attribute__((ext_vector_type(2))) int   i32x2;

__device__ __forceinline__ unsigned short f2bf(float f) {
  union { float f; unsigned u; } x; x.f = f;
  unsigned r = x.u + 0x7fffu + ((x.u >> 16) & 1u);   // RNE to bf16
  return (unsigned short)(r >> 16);
}

__device__ __forceinline__ unsigned pack2(float lo, float hi) {
  __hip_bfloat162 h2 = __float22bfloat162_rn(make_float2(lo, hi));
  return *reinterpret_cast<unsigned*>(&h2);
}

// element (short) offset into a [rows][32] bf16 tile, 16B-chunk XOR swizzle
__device__ __forceinline__ int swz(int row, int ks) {
  return row * 32 + ((ks ^ ((row >> 1) & 3)) << 3);
}

// ---------------- routing ----------------
__global__ void k_zero(int* counts, int* cursor) {
  int i = threadIdx.x;
  if (i < NEXP) { counts[i] = 0; cursor[i] = 0; }
}

__global__ void k_count(const int* __restrict__ idx, int* counts) {
  int t = blockIdx.x * 256 + threadIdx.x;
  if (t >= NTOK) return;
  int e0 = idx[2 * t], e1 = idx[2 * t + 1];
  atomicAdd(&counts[e0], 1);
  if (e1 != e0) atomicAdd(&counts[e1], 1);
}

__global__ void k_scan(const int* __restrict__ counts, int* offsets) {
  if (threadIdx.x == 0) {
    int s = 0;
    for (int e = 0; e < NEXP; e++) { offsets[e] = s; s += counts[e]; }
  }
}

__global__ void k_fill(const int* __restrict__ idx, const float* __restrict__ wts,
                       const int* __restrict__ offsets, int* cursor,
                       int* tokrow, float* wrow, int* rowids) {
  int t = blockIdx.x * 256 + threadIdx.x;
  if (t >= NTOK) return;
  int e0 = idx[2 * t], e1 = idx[2 * t + 1];
  float w0 = wts[2 * t], w1 = wts[2 * t + 1];
  if (e0 == e1) {
    int g = offsets[e0] + atomicAdd(&cursor[e0], 1);
    tokrow[g] = t; wrow[g] = w0 + w1;
    rowids[2 * t] = g; rowids[2 * t + 1] = -1;
  } else {
    int g0 = offsets[e0] + atomicAdd(&cursor[e0], 1);
    tokrow[g0] = t; wrow[g0] = w0;
    int g1 = offsets[e1] + atomicAdd(&cursor[e1], 1);
    tokrow[g1] = t; wrow[g1] = w1;
    rowids[2 * t] = g0; rowids[2 * t + 1] = g1;
  }
}

// ---------------- GEMM1: h = silu(X Wg) * (X Wu), grouped by expert ----------------
__global__ __launch_bounds__(512, 2) void gemm1_kernel(
    const float* __restrict__ X, const float* __restrict__ Wg_all,
    const float* __restrict__ Wu_all, const int* __restrict__ counts,
    const int* __restrict__ offsets, const int* __restrict__ tokrow,
    unsigned short* __restrict__ H) {
  const int e = blockIdx.z;
  const int cnt = counts[e];
  const int m0 = blockIdx.y * 256;
  if (m0 >= cnt) return;
  const int n0 = blockIdx.x * 128;
  const int roff = offsets[e];

  __shared__ __attribute__((aligned(16))) short As[2][8192];
  __shared__ __attribute__((aligned(16))) short Bs[2][2][4096];

  const int tid = threadIdx.x;
  // A staging: 2 threads per row, 16 f32 each
  const int ar  = tid >> 1;
  const int aks = (tid & 1) * 2;
  const int am  = m0 + ar;
  const int atok = (am < cnt) ? tokrow[roff + am] : tokrow[roff];
  const float* __restrict__ xrow = X + (size_t)atok * DM + (tid & 1) * 16;
  // B staging: 4k x 4n block per thread, vectorized along n, transposed in regs
  const int bmat = tid >> 8;                    // 0=Wg 1=Wu
  const int bt   = tid & 255;
  const int bnp  = bt >> 3;                     // 0..31  -> n = bnp*4
  const int bkg  = bt & 7;                      // 0..7   -> k = bkg*4
  const float* __restrict__ bbase =
      (bmat ? Wu_all : Wg_all) + (size_t)e * DM * DF + (size_t)(bkg * 4) * DF + n0 + bnp * 4;

  const int wave = tid >> 6, lane = tid & 63;
  const int wm = wave >> 1, wn = wave & 1;
  const int lr = lane & 15, ks = lane >> 4;

  f32x4 accg[4][4], accu[4][4];
  #pragma unroll
  for (int i = 0; i < 4; i++)
    #pragma unroll
    for (int j = 0; j < 4; j++) {
      accg[i][j] = f32x4{0.f, 0.f, 0.f, 0.f};
      accu[i][j] = f32x4{0.f, 0.f, 0.f, 0.f};
    }

  float aR[16];
  f32x4 bV[4];

  auto loadA = [&](int k0) {
    const f32x4* ap = (const f32x4*)(xrow + k0);
    *(f32x4*)&aR[0]  = ap[0];
    *(f32x4*)&aR[4]  = ap[1];
    *(f32x4*)&aR[8]  = ap[2];
    *(f32x4*)&aR[12] = ap[3];
  };
  auto loadB = [&](int k0) {
    const float* p = bbase + (size_t)k0 * DF;
    bV[0] = *(const f32x4*)(p);
    bV[1] = *(const f32x4*)(p + DF);
    bV[2] = *(const f32x4*)(p + 2 * DF);
    bV[3] = *(const f32x4*)(p + 3 * DF);
  };
  auto writeAB = [&](int b) {
    union { s16x8 s; unsigned u[4]; } q;
    #pragma unroll
    for (int j = 0; j < 4; j++) q.u[j] = pack2(aR[2 * j], aR[2 * j + 1]);
    *(s16x8*)&As[b][swz(ar, aks)] = q.s;
    #pragma unroll
    for (int j = 0; j < 4; j++) q.u[j] = pack2(aR[8 + 2 * j], aR[9 + 2 * j]);
    *(s16x8*)&As[b][swz(ar, aks + 1)] = q.s;
    // B: rotated jn order -> bank-balanced b64 writes
    #pragma unroll
    for (int u = 0; u < 4; u++) {
      int jn  = (u + bnp) & 3;
      int n_j = bnp * 4 + jn;
      i32x2 wv;
      wv[0] = (int)pack2(bV[0][jn], bV[1][jn]);
      wv[1] = (int)pack2(bV[2][jn], bV[3][jn]);
      int off = n_j * 32 + (((bkg >> 1) ^ ((n_j >> 1) & 3)) << 3) + (bkg & 1) * 4;
      *(i32x2*)&Bs[b][bmat][off] = wv;
    }
  };

  loadA(0); loadB(0);
  writeAB(0);
  __syncthreads();
  int buf = 0;
  const int nK = DM / 32;
  for (int kt = 0; kt < nK; ++kt) {
    const bool more = (kt + 1 < nK);
    if (more) { loadA((kt + 1) * 32); loadB((kt + 1) * 32); }  // issue early
    s16x8 af[4], bg[4], bu[4];
    #pragma unroll
    for (int mi = 0; mi < 4; mi++)
      af[mi] = *(const s16x8*)&As[buf][swz(wm * 64 + mi * 16 + lr, ks)];
    #pragma unroll
    for (int ni = 0; ni < 4; ni++) {
      bg[ni] = *(const s16x8*)&Bs[buf][0][swz(wn * 64 + ni * 16 + lr, ks)];
      bu[ni] = *(const s16x8*)&Bs[buf][1][swz(wn * 64 + ni * 16 + lr, ks)];
    }
    #pragma unroll
    for (int mi = 0; mi < 4; mi++)
      #pragma unroll
      for (int ni = 0; ni < 4; ni++) {
        accg[mi][ni] = __builtin_amdgcn_mfma_f32_16x16x32_bf16(af[mi], bg[ni], accg[mi][ni], 0, 0, 0);
        accu[mi][ni] = __builtin_amdgcn_mfma_f32_16x16x32_bf16(af[mi], bu[ni], accu[mi][ni], 0, 0, 0);
      }
    if (more) writeAB(buf ^ 1);   // convert + ds_write late (loads drained under MFMA)
    __syncthreads();
    buf ^= 1;
  }

  #pragma unroll
  for (int mi = 0; mi < 4; mi++) {
    #pragma unroll
    for (int r = 0; r < 4; r++) {
      int row = wm * 64 + mi * 16 + ks * 4 + r;
      if (m0 + row < cnt) {
        unsigned short* hrow = H + (size_t)(roff + m0 + row) * DF + n0 + wn * 64 + lr;
        #pragma unroll
        for (int ni = 0; ni < 4; ni++) {
          float g = accg[mi][ni][r], u = accu[mi][ni][r];
          float sv = g / (1.f + __expf(-g));
          hrow[ni * 16] = f2bf(sv * u);
        }
      }
    }
  }
}

// ---------------- GEMM2: out_pairs = (h Wd) * w_row ----------------
__global__ __launch_bounds__(512, 2) void gemm2_kernel(
    const unsigned short* __restrict__ H, const float* __restrict__ Wd_all,
    const int* __restrict__ counts, const int* __restrict__ offsets,
    const float* __restrict__ wrow, float* __restrict__ OP) {
  const int e = blockIdx.z;
  const int cnt = counts[e];
  const int m0 = blockIdx.y * 256;
  if (m0 >= cnt) return;
  const int n0 = blockIdx.x * 128;
  const int roff = offsets[e];

  __shared__ __attribute__((aligned(16))) short As[2][8192];
  __shared__ __attribute__((aligned(16))) short Bs[2][4096];
  __shared__ float wl[256];

  const int tid = threadIdx.x;
  if (tid < 256) wl[tid] = (m0 + tid < cnt) ? wrow[roff + m0 + tid] : 0.f;

  const int ar  = tid >> 1;
  const int aks = (tid & 1) * 2;
  const int am  = m0 + ar;
  const int arow = (am < cnt) ? (roff + am) : roff;
  const unsigned short* __restrict__ hrow = H + (size_t)arow * DF + (tid & 1) * 16;

  // B staging: 2k x 4n per thread
  const int bnp = tid >> 4;                     // 0..31 -> n = bnp*4
  const int bkg = tid & 15;                     // 0..15 -> k = bkg*2
  const float* __restrict__ bbase =
      Wd_all + (size_t)e * DF * DM + (size_t)(bkg * 2) * DM + n0 + bnp * 4;

  const int wave = tid >> 6, lane = tid & 63;
  const int wm = wave >> 1, wn = wave & 1;
  const int lr = lane & 15, ks = lane >> 4;

  f32x4 acc[4][4];
  #pragma unroll
  for (int i = 0; i < 4; i++)
    #pragma unroll
    for (int j = 0; j < 4; j++) acc[i][j] = f32x4{0.f, 0.f, 0.f, 0.f};

  i32x4 h0, h1;
  f32x4 bV0, bV1;

  auto loadA = [&](int k0) {
    const i32x4* ap = (const i32x4*)(hrow + k0);
    h0 = ap[0]; h1 = ap[1];
  };
  auto loadB = [&](int k0) {
    const float* p = bbase + (size_t)k0 * DM;
    bV0 = *(const f32x4*)(p);
    bV1 = *(const f32x4*)(p + DM);
  };
  auto writeAB = [&](int b) {
    *(i32x4*)&As[b][swz(ar, aks)]     = h0;
    *(i32x4*)&As[b][swz(ar, aks + 1)] = h1;
    #pragma unroll
    for (int u = 0; u < 4; u++) {
      int jn  = (u + bnp) & 3;
      int n_j = bnp * 4 + jn;
      unsigned wv = pack2(bV0[jn], bV1[jn]);
      int off = n_j * 32 + (((bkg >> 2) ^ ((n_j >> 1) & 3)) << 3) + (bkg & 3) * 2;
      *(unsigned*)&Bs[b][off] = wv;
    }
  };

  loadA(0); loadB(0);
  writeAB(0);
  __syncthreads();
  int buf = 0;
  const int nK = DF / 32;
  for (int kt = 0; kt < nK; ++kt) {
    const bool more = (kt + 1 < nK);
    if (more) { loadA((kt + 1) * 32); loadB((kt + 1) * 32); }
    s16x8 af[4], bf_[4];
    #pragma unroll
    for (int mi = 0; mi < 4; mi++)
      af[mi] = *(const s16x8*)&As[buf][swz(wm * 64 + mi * 16 + lr, ks)];
    #pragma unroll
    for (int ni = 0; ni < 4; ni++)
      bf_[ni] = *(const s16x8*)&Bs[buf][swz(wn * 64 + ni * 16 + lr, ks)];
    #pragma unroll
    for (int mi = 0; mi < 4; mi++)
      #pragma unroll
      for (int ni = 0; ni < 4; ni++)
        acc[mi][ni] = __builtin_amdgcn_mfma_f32_16x16x32_bf16(af[mi], bf_[ni], acc[mi][ni], 0, 0, 0);
    if (more) writeAB(buf ^ 1);
    __syncthreads();
    buf ^= 1;
  }

  #pragma unroll
  for (int mi = 0; mi < 4; mi++) {
    #pragma unroll
    for (int r = 0; r < 4; r++) {
      int row = wm * 64 + mi * 16 + ks * 4 + r;
      if (m0 + row < cnt) {
        float wgt = wl[row];
        float* orow = OP + (size_t)(roff + m0 + row) * DM + n0 + wn * 64 + lr;
        #pragma unroll
        for (int ni = 0; ni < 4; ni++) orow[ni * 16] = acc[mi][ni][r] * wgt;
      }
    }
  }
}

// ---------------- combine: out[t] = sum of the token's (<=2) weighted rows ----------------
__global__ void k_combine(const float* __restrict__ OP, const int* __restrict__ rowids,
                          float* __restrict__ out) {
  int gid = blockIdx.x * 256 + threadIdx.x;
  if (gid >= NTOK * DM / 4) return;
  int t = gid >> 9;
  int c = (gid & 511) << 2;
  int r0 = rowids[2 * t], r1 = rowids[2 * t + 1];
  f32x4 v = *(const f32x4*)(OP + (size_t)r0 * DM + c);
  if (r1 >= 0) {
    f32x4 v1 = *(const f32x4*)(OP + (size_t)r1 * DM + c);
    v = v + v1;
  }
  *(f32x4*)(out + (size_t)t * DM + c) = v;
}

extern "C" void kernel_launch(void* const* d_in, const int* in_sizes, int n_in,
                              void* d_out, int out_size, void* d_ws, size_t ws_size,
                              hipStream_t stream) {
  (void)in_sizes; (void)n_in; (void)out_size; (void)ws_size;
  const float* X   = (const float*)d_in[0];
  const int*   idx = (const int*)d_in[1];
  const float* wts = (const float*)d_in[2];
  const float* Wg  = (const float*)d_in[3];
  const float* Wu  = (const float*)d_in[4];
  const float* Wd  = (const float*)d_in[5];
  float* out = (float*)d_out;

  uint8_t* w = (uint8_t*)d_ws;
  int*   counts  = (int*)(w + 0);
  int*   cursor  = (int*)(w + 64);
  int*   offsets = (int*)(w + 128);
  int*   tokrow  = (int*)(w + 256);
  float* wrow    = (float*)(w + 256 + 4 * 8192);
  int*   rowids  = (int*)(w + 256 + 8 * 8192);
  unsigned short* H = (unsigned short*)(w + 131072);
  float* OP = (float*)(w + 131072 + (size_t)8192 * DF * 2);

  k_zero<<<1, 64, 0, stream>>>(counts, cursor);
  k_count<<<16, 256, 0, stream>>>(idx, counts);
  k_scan<<<1, 64, 0, stream>>>(counts, offsets);
  k_fill<<<16, 256, 0, stream>>>(idx, wts, offsets, cursor, tokrow, wrow, rowids);
  gemm1_kernel<<<dim3(DF / 128, 16, NEXP), 512, 0, stream>>>(X, Wg, Wu, counts, offsets, tokrow, H);
  gemm2_kernel<<<dim3(DM / 128, 16, NEXP), 512, 0, stream>>>(H, Wd, counts, offsets, wrow, OP);
  k_combine<<<(NTOK * DM / 4) / 256, 256, 0, stream>>>(OP, rowids, out);
}